// Round 1
// baseline (282.945 us; speedup 1.0000x reference)
//
#include <hip/hip_runtime.h>

#define IMG_W 512
#define IMG_H 512
#define TY 8
#define PLANES 96              // N*C = 32*3
#define NPIX (32ll * 3 * 512 * 512)

// Horizontal/vertical separable Gaussian, sigma=1.5, size=11, normalized.
// Values folded at compile time (all loop indices constant after unroll).
#define WG_INIT { 0.00102838f, 0.00759876f, 0.03600077f, 0.10936069f, \
                  0.21300553f, 0.26601172f, 0.21300553f, 0.10936069f, \
                  0.03600077f, 0.00759876f, 0.00102838f }

__global__ __launch_bounds__(512, 4)
void ssim_main(const float* __restrict__ pred, const float* __restrict__ targ,
               double* __restrict__ acc) {
    const float WG[11] = WG_INIT;

    // 5 maps x 4 rows x (8 pad | 512 data | 8 pad) columns
    __shared__ __align__(16) float maps[5][4][528];
    __shared__ float wsum[8];

    const int tid   = threadIdx.x;
    const int x     = tid;                 // column this thread owns (vertical pass)
    const int plane = blockIdx.y;
    const int y0    = blockIdx.x * TY;
    const size_t base = (size_t)plane * (IMG_W * IMG_H);

    // Zero the horizontal halo pads (cols 0..7 and 520..527) once.
    // Data writes only touch cols [8,520), so pads stay zero for both chunks.
    if (tid < 320) {
        int m  = tid >> 6;            // 0..4
        int rr = (tid & 63) >> 4;     // 0..3
        int cc = tid & 15;            // 0..15
        int c  = (cc < 8) ? cc : (512 + cc);
        maps[m][rr][c] = 0.f;
    }

    // ---- vertical pass: 18 input rows -> 8 output rows, all in registers ----
    float aP[TY], aT[TY], aPP[TY], aTT[TY], aPT[TY];
#pragma unroll
    for (int i = 0; i < TY; ++i) { aP[i]=0.f; aT[i]=0.f; aPP[i]=0.f; aTT[i]=0.f; aPT[i]=0.f; }

#pragma unroll
    for (int iy = 0; iy < TY + 10; ++iy) {
        int y = y0 - 5 + iy;
        float p = 0.f, t = 0.f;
        if ((unsigned)y < (unsigned)IMG_H) {      // wave-uniform branch
            p = pred[base + (size_t)y * IMG_W + x];
            t = targ[base + (size_t)y * IMG_W + x];
        }
        float pp = p * p, tt = t * t, pt = p * t;
#pragma unroll
        for (int oy = 0; oy < TY; ++oy) {
            int k = iy - oy;                      // compile-time
            if (0 <= k && k <= 10) {
                float wk = WG[k];
                aP [oy] = fmaf(wk, p,  aP [oy]);
                aT [oy] = fmaf(wk, t,  aT [oy]);
                aPP[oy] = fmaf(wk, pp, aPP[oy]);
                aTT[oy] = fmaf(wk, tt, aTT[oy]);
                aPT[oy] = fmaf(wk, pt, aPT[oy]);
            }
        }
    }

    // ---- horizontal pass + SSIM, two 4-row chunks through LDS ----
    const float C1 = 1e-4f, C2 = 9e-4f;
    float lsum = 0.f;

#pragma unroll
    for (int half = 0; half < 2; ++half) {
        __syncthreads();   // pads ready (1st) / previous chunk consumed (2nd)
        {
            int c = x + 8;
#pragma unroll
            for (int r = 0; r < 4; ++r) {
                int oy = half * 4 + r;
                maps[0][r][c] = aP [oy];
                maps[1][r][c] = aT [oy];
                maps[2][r][c] = aPP[oy];
                maps[3][r][c] = aTT[oy];
                maps[4][r][c] = aPT[oy];
            }
        }
        __syncthreads();

        // 4 rows x 512 cols = 2048 px; 4 consecutive px per thread
        int r  = tid >> 7;             // 0..3
        int x0 = (tid & 127) * 4;      // 0,4,...,508

        float h[5][4];
#pragma unroll
        for (int m = 0; m < 5; ++m) {
            float f[20];
#pragma unroll
            for (int q = 0; q < 5; ++q) {
                const float4 v = *(const float4*)&maps[m][r][x0 + 4 * q];
                f[4*q+0] = v.x; f[4*q+1] = v.y; f[4*q+2] = v.z; f[4*q+3] = v.w;
            }
#pragma unroll
            for (int j = 0; j < 4; ++j) {
                float s = 0.f;
#pragma unroll
                for (int k = 0; k < 11; ++k)
                    s = fmaf(WG[k], f[3 + j + k], s);
                h[m][j] = s;
            }
        }

#pragma unroll
        for (int j = 0; j < 4; ++j) {
            float mu1 = h[0][j], mu2 = h[1][j];
            float mu1s = mu1 * mu1, mu2s = mu2 * mu2, mu12 = mu1 * mu2;
            float s1  = h[2][j] - mu1s;
            float s2  = h[3][j] - mu2s;
            float s12 = h[4][j] - mu12;
            float num = (2.f * mu12 + C1) * (2.f * s12 + C2);
            float den = (mu1s + mu2s + C1) * (s1 + s2 + C2) + 1e-8f;
            lsum += num / den;
        }
    }

    // ---- reduction: wave shuffle -> LDS -> one double atomic per block ----
#pragma unroll
    for (int off = 32; off > 0; off >>= 1)
        lsum += __shfl_down(lsum, off);
    if ((tid & 63) == 0) wsum[tid >> 6] = lsum;
    __syncthreads();
    if (tid == 0) {
        float s = 0.f;
#pragma unroll
        for (int i = 0; i < 8; ++i) s += wsum[i];
        atomicAdd(acc, (double)s);
    }
}

__global__ void ssim_final(const double* __restrict__ acc, float* __restrict__ out) {
    out[0] = 1.0f - (float)(acc[0] * (1.0 / (double)NPIX));
}

extern "C" void kernel_launch(void* const* d_in, const int* in_sizes, int n_in,
                              void* d_out, int out_size, void* d_ws, size_t ws_size,
                              hipStream_t stream) {
    const float* pred = (const float*)d_in[0];
    const float* targ = (const float*)d_in[1];
    double* acc = (double*)d_ws;

    hipMemsetAsync(acc, 0, sizeof(double), stream);

    dim3 grid(IMG_H / TY, PLANES);   // strips adjacent in dispatch -> halo L2 reuse
    ssim_main<<<grid, 512, 0, stream>>>(pred, targ, acc);
    ssim_final<<<1, 1, 0, stream>>>(acc, (float*)d_out);
}